// Round 2
// baseline (8708.364 us; speedup 1.0000x reference)
//
#include <hip/hip_runtime.h>
#include <hip/hip_bf16.h>

typedef __hip_bfloat16 bf16;

#define V_    32000
#define E_    512
#define H_    512
#define T_    128
#define B_    4
#define D_    4
#define L_    2
#define C0_   2000
#define C1_   10000
#define NT_   125
#define NROW_ 2000          // B*NT*D
#define NH_   2002          // head classes
#define NTOT_ 2162          // 2002 head + 128 proj0 + 32 proj1

__device__ __forceinline__ float bf2f(bf16 v) { return __bfloat162float(v); }

__device__ __forceinline__ unsigned short f2bfu(float f) {
    bf16 h = __float2bfloat16(f);
    union { bf16 h; unsigned short u; } cv; cv.h = h; return cv.u;
}

__device__ __forceinline__ void up8(uint4 u, float* a) {
    a[0] = __uint_as_float(u.x << 16); a[1] = __uint_as_float(u.x & 0xffff0000u);
    a[2] = __uint_as_float(u.y << 16); a[3] = __uint_as_float(u.y & 0xffff0000u);
    a[4] = __uint_as_float(u.z << 16); a[5] = __uint_as_float(u.z & 0xffff0000u);
    a[6] = __uint_as_float(u.w << 16); a[7] = __uint_as_float(u.w & 0xffff0000u);
}

// dtype-flag helpers: bf==1 -> data is bf16, bf==0 -> data is float32
__device__ __forceinline__ float ld1(const void* p, size_t i, int bf) {
    return bf ? bf2f(((const bf16*)p)[i]) : ((const float*)p)[i];
}
__device__ __forceinline__ void ld8(const void* p, size_t i, int bf, float* a) {
    if (bf) { uint4 u = *(const uint4*)((const bf16*)p + i); up8(u, a); }
    else {
        const float4* q = (const float4*)((const float*)p + i);
        float4 x = q[0], y = q[1];
        a[0]=x.x; a[1]=x.y; a[2]=x.z; a[3]=x.w; a[4]=y.x; a[5]=y.y; a[6]=y.z; a[7]=y.w;
    }
}
__device__ __forceinline__ void st1(void* p, size_t i, int bf, float v) {
    if (bf) ((unsigned short*)p)[i] = f2bfu(v);
    else    ((float*)p)[i] = v;
}

__device__ __forceinline__ float dot8(const float* a, float4 xa, float4 xb, float acc) {
    acc = fmaf(a[0], xa.x, acc); acc = fmaf(a[1], xa.y, acc);
    acc = fmaf(a[2], xa.z, acc); acc = fmaf(a[3], xa.w, acc);
    acc = fmaf(a[4], xb.x, acc); acc = fmaf(a[5], xb.y, acc);
    acc = fmaf(a[6], xb.z, acc); acc = fmaf(a[7], xb.w, acc);
    return acc;
}

__device__ __forceinline__ void lse_push(float z, float& m, float& s) {
    if (z <= m) { s += __expf(z - m); }
    else        { s = s * __expf(m - z) + 1.0f; m = z; }
}
__device__ __forceinline__ void lse_merge(float m2, float s2, float& m, float& s) {
    float mm = fmaxf(m, m2);
    s = s * __expf(m - mm) + s2 * __expf(m2 - mm);
    m = mm;
}

// ---------------- stage 0: dtype detect ----------------
// G[0,0,0,:] is a softmax row over T_=128 -> sums to 1.0 in the true dtype.
__global__ void k_detect(const void* __restrict__ G, int* __restrict__ flag) {
    int t = threadIdx.x;   // 64 threads
    float s32 = 0.0f, s16 = 0.0f;
    for (int k = t; k < 128; k += 64) {
        s32 += ((const float*)G)[k];
        s16 += bf2f(((const bf16*)G)[k]);
    }
    for (int off = 32; off; off >>= 1) {
        s32 += __shfl_down(s32, off);
        s16 += __shfl_down(s16, off);
    }
    if (t == 0) {
        float e32 = fabsf(s32 - 1.0f);
        // if reading as f32 gives a row-sum ~1, it's f32; else bf16.
        // NaN/inf in e32 compares false -> bf16, which is the correct fallback.
        *flag = (e32 < 0.05f) ? 0 : 1;
    }
}

// ---------------- stage A: embedding gather ----------------
__global__ void k_embed(const int* __restrict__ x, const void* __restrict__ emb,
                        float* __restrict__ embedded, float* __restrict__ f0,
                        const int* __restrict__ flagp) {
    const int bf = *flagp;
    int i = blockIdx.x * 256 + threadIdx.x;          // B*T*E = 262144 threads
    int bt = i >> 9, e = i & 511;
    int tok = x[bt];
    float v = ld1(emb, (size_t)tok * E_ + e, bf);
    embedded[i] = v; f0[i] = v;
}

// ---------------- stage B: wgt[b,i,e] = sum_j G[b,l,j,i] f[b,j,e] ----------------
__global__ void k_wgt(const void* __restrict__ G, const float* __restrict__ f,
                      float* __restrict__ wgt, int l, const int* __restrict__ flagp) {
    const int bf = *flagp;
    int i = blockIdx.x * 256 + threadIdx.x;          // 262144
    int e = i & 511;
    int bi = i >> 9;            // b*T + ipos
    int b = bi >> 7, ip = bi & 127;
    size_t gbase = ((size_t)(b * L_ + l) * T_ * T_) + ip;   // stride T_ over j
    const float* fb = f + (size_t)b * T_ * E_ + e;          // stride E_ over j
    float acc = 0.0f;
    #pragma unroll 4
    for (int j = 0; j < T_; ++j)
        acc = fmaf(ld1(G, gbase + (size_t)j * T_, bf), fb[(size_t)j * E_], acc);
    wgt[i] = acc;
}

// ---------------- GRU gate GEMV ----------------
__global__ void k_gates(const void* __restrict__ Wi, const void* __restrict__ Wh,
                        const void* __restrict__ Bi, const void* __restrict__ Bh,
                        size_t woff, size_t boff,
                        const float* __restrict__ X, const float* __restrict__ Hst,
                        float* __restrict__ gates, const int* __restrict__ flagp) {
    const int bf = *flagp;
    const int row = blockIdx.x;
    const int t = threadIdx.x;
    __shared__ __align__(16) float xs[512];
    float* grow = gates + (size_t)row * 3072;
    for (int ph = 0; ph < 2; ++ph) {
        const float* src = ph ? (Hst + (size_t)row * 512) : (X + (size_t)row * 512);
        const void* W  = ph ? Wh : Wi;
        const void* Bb = ph ? Bh : Bi;
        __syncthreads();
        for (int k = t; k < 512; k += 256) xs[k] = src[k];
        __syncthreads();
        const float4* xs4 = (const float4*)xs;
        float acc[6];
        #pragma unroll
        for (int cc = 0; cc < 6; ++cc) acc[cc] = ld1(Bb, boff + t + cc * 256, bf);
        for (int k8 = 0; k8 < 64; ++k8) {
            float4 xa = xs4[2 * k8], xb = xs4[2 * k8 + 1];
            #pragma unroll
            for (int cc = 0; cc < 6; ++cc) {
                float a[8];
                ld8(W, woff + (((size_t)(t + cc * 256)) << 9) + (k8 << 3), bf, a);
                acc[cc] = dot8(a, xa, xb, acc[cc]);
            }
        }
        #pragma unroll
        for (int cc = 0; cc < 6; ++cc) grow[ph * 1536 + t + cc * 256] = acc[cc];
    }
}

__device__ __forceinline__ float gru_out(const float* grow, int k, float h) {
    float i_r = grow[k], i_z = grow[512 + k], i_n = grow[1024 + k];
    float h_r = grow[1536 + k], h_z = grow[2048 + k], h_n = grow[2560 + k];
    float r = 1.0f / (1.0f + __expf(-(i_r + h_r)));
    float z = 1.0f / (1.0f + __expf(-(i_z + h_z)));
    float n = tanhf(i_n + r * h_n);
    return (1.0f - z) * n + z * h;
}

__global__ void k_apply_enc(const float* __restrict__ gates, const float* __restrict__ hprev,
                            float* __restrict__ hnext) {
    int i = blockIdx.x * 256 + threadIdx.x;          // 262144
    int row = i >> 9, k = i & 511;
    hnext[i] = gru_out(gates + (size_t)row * 3072, k, hprev[i]);
}

// ---------------- decoder prep ----------------
__global__ void k_h0(const float* __restrict__ ffin, float* __restrict__ hdec) {
    int i = blockIdx.x * 256 + threadIdx.x;          // 500*512 = 256000
    int row = i >> 9, e = i & 511;
    int b = row / NT_, t = row - b * NT_;
    hdec[i] = ffin[((size_t)(b * T_ + t) << 9) + e];
}

__global__ void k_win(const float* __restrict__ embedded, const int* __restrict__ lengths,
                      float* __restrict__ win, int d) {
    int i = blockIdx.x * 256 + threadIdx.x;          // 256000
    int row = i >> 9, e = i & 511;
    int b = row / NT_, t = row - b * NT_;
    int tok = (d == 0 && t == 0) ? (lengths[b] - 1) : (t + d - 1);
    win[i] = embedded[((size_t)(b * T_ + tok) << 9) + e];
}

__global__ void k_apply_dec(const float* __restrict__ gates, float* __restrict__ hdec,
                            float* __restrict__ hs, const int* __restrict__ lengths, int d) {
    int i = blockIdx.x * 256 + threadIdx.x;          // 256000
    int row = i >> 9, k = i & 511;
    int b = row / NT_, t = row - b * NT_;
    float hn = gru_out(gates + (size_t)row * 3072, k, hdec[i]);
    hdec[i] = hn;
    bool valid = (t + d) < lengths[b];
    hs[(((size_t)row * D_ + d) << 9) + k] = valid ? hn : 0.0f;   // r = b*500 + t*4 + d
}

// ---------------- stage E1: head logits + projections, online LSE ----------------
__global__ void k_head(const float* __restrict__ hsrows, const void* __restrict__ head_w,
                       const void* __restrict__ t0_proj, const void* __restrict__ t1_proj,
                       void* __restrict__ out, float* __restrict__ proj0,
                       float* __restrict__ proj1, float* __restrict__ stats,
                       const int* __restrict__ flagp) {
    const int bf = *flagp;
    int r = blockIdx.x;
    int t = threadIdx.x;
    __shared__ __align__(16) float xs[512];
    const float* hrow = hsrows + (size_t)r * 512;
    for (int k = t; k < 512; k += 256) xs[k] = hrow[k];
    __syncthreads();
    const float4* xs4 = (const float4*)xs;
    float m = -1e30f, s = 0.0f;
    for (int c = t; c < NTOT_; c += 256) {
        const void* W; size_t base;
        if (c < NH_)            { W = head_w;  base = ((size_t)c << 9); }
        else if (c < NH_ + 128) { W = t0_proj; base = ((size_t)(c - NH_) << 9); }
        else                    { W = t1_proj; base = ((size_t)(c - NH_ - 128) << 9); }
        float acc = 0.0f;
        for (int k8 = 0; k8 < 64; ++k8) {
            float a[8];
            ld8(W, base + (k8 << 3), bf, a);
            acc = dot8(a, xs4[2 * k8], xs4[2 * k8 + 1], acc);
        }
        if (c < NH_) {
            lse_push(acc, m, s);
            if (c < C0_) st1(out, (size_t)r * V_ + c, bf, acc);
            else stats[r * 8 + 2 + (c - C0_)] = acc;    // z at class 2000 / 2001
        } else if (c < NH_ + 128) proj0[r * 128 + (c - NH_)] = acc;
        else proj1[r * 32 + (c - NH_ - 128)] = acc;
    }
    __shared__ float sm[256], ss[256];
    sm[t] = m; ss[t] = s;
    __syncthreads();
    for (int w = 128; w > 0; w >>= 1) {
        if (t < w) { float mm = sm[t], sss = ss[t]; lse_merge(sm[t + w], ss[t + w], mm, sss); sm[t] = mm; ss[t] = sss; }
        __syncthreads();
    }
    if (t == 0) { stats[r * 8 + 0] = sm[0]; stats[r * 8 + 1] = ss[0]; }
}

// ---------------- stage E2/E3: tail logits + LSE ----------------
__global__ void k_tail0(const float* __restrict__ proj0, const void* __restrict__ t0_out,
                        void* __restrict__ out, float* __restrict__ stats,
                        const int* __restrict__ flagp) {
    const int bf = *flagp;
    int r = blockIdx.x, t = threadIdx.x;
    __shared__ __align__(16) float xs[128];
    if (t < 128) xs[t] = proj0[r * 128 + t];
    __syncthreads();
    const float4* xs4 = (const float4*)xs;
    float m = -1e30f, s = 0.0f;
    for (int j = t; j < 8000; j += 256) {
        float acc = 0.0f;
        #pragma unroll
        for (int k8 = 0; k8 < 16; ++k8) {
            float a[8];
            ld8(t0_out, ((size_t)j << 7) + (k8 << 3), bf, a);
            acc = dot8(a, xs4[2 * k8], xs4[2 * k8 + 1], acc);
        }
        lse_push(acc, m, s);
        st1(out, (size_t)r * V_ + C0_ + j, bf, acc);
    }
    __shared__ float sm[256], ss[256];
    sm[t] = m; ss[t] = s;
    __syncthreads();
    for (int w = 128; w > 0; w >>= 1) {
        if (t < w) { float mm = sm[t], sss = ss[t]; lse_merge(sm[t + w], ss[t + w], mm, sss); sm[t] = mm; ss[t] = sss; }
        __syncthreads();
    }
    if (t == 0) { stats[r * 8 + 4] = sm[0]; stats[r * 8 + 5] = ss[0]; }
}

__global__ void k_tail1(const float* __restrict__ proj1, const void* __restrict__ t1_out,
                        void* __restrict__ out, float* __restrict__ stats,
                        const int* __restrict__ flagp) {
    const int bf = *flagp;
    int r = blockIdx.x, t = threadIdx.x;
    __shared__ __align__(16) float xs[32];
    if (t < 32) xs[t] = proj1[r * 32 + t];
    __syncthreads();
    const float4* xs4 = (const float4*)xs;
    float m = -1e30f, s = 0.0f;
    for (int j = t; j < 22000; j += 256) {
        float acc = 0.0f;
        #pragma unroll
        for (int k8 = 0; k8 < 4; ++k8) {
            float a[8];
            ld8(t1_out, ((size_t)j << 5) + (k8 << 3), bf, a);
            acc = dot8(a, xs4[2 * k8], xs4[2 * k8 + 1], acc);
        }
        lse_push(acc, m, s);
        st1(out, (size_t)r * V_ + C1_ + j, bf, acc);
    }
    __shared__ float sm[256], ss[256];
    sm[t] = m; ss[t] = s;
    __syncthreads();
    for (int w = 128; w > 0; w >>= 1) {
        if (t < w) { float mm = sm[t], sss = ss[t]; lse_merge(sm[t + w], ss[t + w], mm, sss); sm[t] = mm; ss[t] = sss; }
        __syncthreads();
    }
    if (t == 0) { stats[r * 8 + 6] = sm[0]; stats[r * 8 + 7] = ss[0]; }
}

// ---------------- per-row corrections ----------------
__global__ void k_corr(const float* __restrict__ stats, float* __restrict__ corr) {
    int r = blockIdx.x * 256 + threadIdx.x;
    if (r >= NROW_) return;
    float ch  = stats[r * 8 + 0] + __logf(stats[r * 8 + 1]);       // head lse
    float lp0 = stats[r * 8 + 2] - ch;                              // head_lp[C0]
    float lp1 = stats[r * 8 + 3] - ch;                              // head_lp[C0+1]
    corr[r * 4 + 0] = ch;
    corr[r * 4 + 1] = stats[r * 8 + 4] + __logf(stats[r * 8 + 5]) - lp0;
    corr[r * 4 + 2] = stats[r * 8 + 6] + __logf(stats[r * 8 + 7]) - lp1;
}

// ---------------- final: out = z - corr, zero invalid rows ----------------
__global__ void k_final(void* __restrict__ out, const float* __restrict__ corr,
                        const int* __restrict__ lengths, const int* __restrict__ flagp) {
    const int bf = *flagp;
    size_t vec = (size_t)blockIdx.x * 256 + threadIdx.x;   // 8,000,000 vecs of 8
    size_t base = vec << 3;
    int r = (int)(base / V_);
    int c = (int)(base - (size_t)r * V_);
    int b = r / 500;
    int t = (r - b * 500) >> 2;
    if (t >= lengths[b]) {
        if (bf) { uint4 z; z.x = z.y = z.z = z.w = 0u; *(uint4*)((unsigned short*)out + base) = z; }
        else { float4 z; z.x = z.y = z.z = z.w = 0.0f;
               float4* p = (float4*)((float*)out + base); p[0] = z; p[1] = z; }
        return;
    }
    float cr = (c < C0_) ? corr[r * 4 + 0] : ((c < C1_) ? corr[r * 4 + 1] : corr[r * 4 + 2]);
    float a[8]; ld8(out, base, bf, a);
    if (bf) {
        unsigned short o[8];
        #pragma unroll
        for (int q = 0; q < 8; ++q) o[q] = f2bfu(a[q] - cr);
        uint4 w;
        w.x = (unsigned)o[0] | ((unsigned)o[1] << 16);
        w.y = (unsigned)o[2] | ((unsigned)o[3] << 16);
        w.z = (unsigned)o[4] | ((unsigned)o[5] << 16);
        w.w = (unsigned)o[6] | ((unsigned)o[7] << 16);
        *(uint4*)((unsigned short*)out + base) = w;
    } else {
        float4 p0, p1;
        p0.x = a[0] - cr; p0.y = a[1] - cr; p0.z = a[2] - cr; p0.w = a[3] - cr;
        p1.x = a[4] - cr; p1.y = a[5] - cr; p1.z = a[6] - cr; p1.w = a[7] - cr;
        float4* p = (float4*)((float*)out + base);
        p[0] = p0; p[1] = p1;
    }
}

// ---------------- workspace layout (float offsets) ----------------
#define WS_EMB   0
#define WS_FA    262144
#define WS_FB    524288
#define WS_WGT   786432
#define WS_GATES 1048576
#define WS_HDEC  2621440
#define WS_WIN   2877440
#define WS_HS    3133440
#define WS_P0    4157440
#define WS_P1    4413440
#define WS_STATS 4477440
#define WS_CORR  4493440
#define WS_FLAG  4501440

extern "C" void kernel_launch(void* const* d_in, const int* in_sizes, int n_in,
                              void* d_out, int out_size, void* d_ws, size_t ws_size,
                              hipStream_t stream) {
    (void)in_sizes; (void)n_in; (void)out_size; (void)ws_size;
    const int*  x        = (const int*)d_in[0];
    const int*  lengths  = (const int*)d_in[1];
    const void* G        = d_in[2];
    const void* emb      = d_in[3];
    const void* enc_w_ih = d_in[4];
    const void* enc_w_hh = d_in[5];
    const void* enc_b_ih = d_in[6];
    const void* enc_b_hh = d_in[7];
    const void* dec_w_ih = d_in[8];
    const void* dec_w_hh = d_in[9];
    const void* dec_b_ih = d_in[10];
    const void* dec_b_hh = d_in[11];
    const void* head_w   = d_in[12];
    const void* t0_proj  = d_in[13];
    const void* t0_out   = d_in[14];
    const void* t1_proj  = d_in[15];
    const void* t1_out   = d_in[16];

    float* ws = (float*)d_ws;
    float* embedded = ws + WS_EMB;
    float* fA   = ws + WS_FA;
    float* fB   = ws + WS_FB;
    float* wgt  = ws + WS_WGT;
    float* gates= ws + WS_GATES;
    float* hdec = ws + WS_HDEC;
    float* win  = ws + WS_WIN;
    float* hs   = ws + WS_HS;
    float* p0   = ws + WS_P0;
    float* p1   = ws + WS_P1;
    float* stats= ws + WS_STATS;
    float* corr = ws + WS_CORR;
    int*  flagp = (int*)(ws + WS_FLAG);
    void* out   = d_out;

    k_detect<<<1, 64, 0, stream>>>(G, flagp);
    k_embed<<<1024, 256, 0, stream>>>(x, emb, embedded, fA, flagp);

    // encoder layer 0: fA -> fB
    k_wgt<<<1024, 256, 0, stream>>>(G, fA, wgt, 0, flagp);
    k_gates<<<512, 256, 0, stream>>>(enc_w_ih, enc_w_hh, enc_b_ih, enc_b_hh,
                                     0, 0, wgt, fA, gates, flagp);
    k_apply_enc<<<1024, 256, 0, stream>>>(gates, fA, fB);
    // encoder layer 1: fB -> fA
    k_wgt<<<1024, 256, 0, stream>>>(G, fB, wgt, 1, flagp);
    k_gates<<<512, 256, 0, stream>>>(enc_w_ih, enc_w_hh, enc_b_ih, enc_b_hh,
                                     (size_t)1536 * 512, 1536, wgt, fB, gates, flagp);
    k_apply_enc<<<1024, 256, 0, stream>>>(gates, fB, fA);

    k_h0<<<1000, 256, 0, stream>>>(fA, hdec);
    for (int d = 0; d < D_; ++d) {
        k_win<<<1000, 256, 0, stream>>>(embedded, lengths, win, d);
        k_gates<<<500, 256, 0, stream>>>(dec_w_ih, dec_w_hh, dec_b_ih, dec_b_hh,
                                         0, 0, win, hdec, gates, flagp);
        k_apply_dec<<<1000, 256, 0, stream>>>(gates, hdec, hs, lengths, d);
    }

    k_head<<<NROW_, 256, 0, stream>>>(hs, head_w, t0_proj, t1_proj, out, p0, p1, stats, flagp);
    k_tail0<<<NROW_, 256, 0, stream>>>(p0, t0_out, out, stats, flagp);
    k_tail1<<<NROW_, 256, 0, stream>>>(p1, t1_out, out, stats, flagp);
    k_corr<<<8, 256, 0, stream>>>(stats, corr);
    k_final<<<31250, 256, 0, stream>>>(out, corr, lengths, flagp);
}

// Round 3
// 925.417 us; speedup vs baseline: 9.4102x; 9.4102x over previous
//
#include <hip/hip_runtime.h>
#include <hip/hip_bf16.h>

typedef __hip_bfloat16 bf16;
typedef __attribute__((ext_vector_type(8))) short short8v;
typedef __attribute__((ext_vector_type(4))) float float4v;

#define V_    32000
#define E_    512
#define H_    512
#define T_    128
#define B_    4
#define D_    4
#define L_    2
#define C0_   2000
#define C1_   10000
#define NT_   125
#define NROW_ 2000          // B*NT*D
#define NH_   2002
#define NTOTC 2162          // 2002 + 128 + 32
#define NSLOT 252           // 17 head + 63 t0 + 172 t1 LSE partial slots per row

__device__ __forceinline__ float bf2f(bf16 v) { return __bfloat162float(v); }
__device__ __forceinline__ unsigned short f2bfu(float f) {
    bf16 h = __float2bfloat16(f);
    union { bf16 h; unsigned short u; } cv; cv.h = h; return cv.u;
}
__device__ __forceinline__ float ubf2f(unsigned short u) {
    return __uint_as_float(((unsigned)u) << 16);
}
// dtype-flag helpers: bf==1 -> bf16 input data, bf==0 -> float32
__device__ __forceinline__ float ld1(const void* p, size_t i, int bf) {
    return bf ? bf2f(((const bf16*)p)[i]) : ((const float*)p)[i];
}
__device__ __forceinline__ void st1(void* p, size_t i, int bf, float v) {
    if (bf) ((unsigned short*)p)[i] = f2bfu(v);
    else    ((float*)p)[i] = v;
}

__device__ __forceinline__ void lse_push(float z, float& m, float& s) {
    if (z <= m) { s += __expf(z - m); }
    else        { s = s * __expf(m - z) + 1.0f; m = z; }
}
__device__ __forceinline__ void lse_merge(float m2, float s2, float& m, float& s) {
    float mm = fmaxf(m, m2);
    s = s * __expf(m - mm) + s2 * __expf(m2 - mm);
    m = mm;
}

// ---------------- stage 0: dtype detect (G row 0 is a softmax row) --------
__global__ void k_detect(const void* __restrict__ G, int* __restrict__ flag) {
    int t = threadIdx.x;   // 64 threads
    float s32 = 0.0f;
    for (int k = t; k < 128; k += 64) s32 += ((const float*)G)[k];
    for (int off = 32; off; off >>= 1) s32 += __shfl_down(s32, off);
    if (t == 0) {
        float e32 = fabsf(s32 - 1.0f);
        *flag = (e32 < 0.05f) ? 0 : 1;   // NaN compares false -> bf16 fallback
    }
}

// ---------------- weight conversion: all weights -> one contiguous bf16 region
struct ConvArgs {
    const void* src[9];
    unsigned int off[10];
};
__global__ void k_wconv(ConvArgs a, unsigned short* __restrict__ wb,
                        const int* __restrict__ flagp) {
    const int bf = *flagp;
    unsigned int total = a.off[9];
    for (unsigned int i = blockIdx.x * 256 + threadIdx.x; i < total;
         i += gridDim.x * 256) {
        int seg = 0;
        while (i >= a.off[seg + 1]) seg++;
        wb[i] = f2bfu(ld1(a.src[seg], i - a.off[seg], bf));
    }
}

// ---------------- embedding gather ----------------
__global__ void k_embed(const int* __restrict__ x, const void* __restrict__ emb,
                        float* __restrict__ embedded, float* __restrict__ f0,
                        unsigned short* __restrict__ f0b,
                        const int* __restrict__ flagp) {
    const int bf = *flagp;
    int i = blockIdx.x * 256 + threadIdx.x;          // 262144
    int bt = i >> 9, e = i & 511;
    int tok = x[bt];
    float v = ld1(emb, (size_t)tok * E_ + e, bf);
    embedded[i] = v; f0[i] = v; f0b[i] = f2bfu(v);
}

// ---------------- wgt[b,i,e] = sum_j G[b,l,j,i] f[b,j,e]  (f32 acc, bf16 out)
__global__ void k_wgt(const void* __restrict__ G, const float* __restrict__ f,
                      unsigned short* __restrict__ wgtb, int l,
                      const int* __restrict__ flagp) {
    const int bf = *flagp;
    int i = blockIdx.x * 256 + threadIdx.x;          // 262144
    int e = i & 511;
    int bi = i >> 9;
    int b = bi >> 7, ip = bi & 127;
    size_t gbase = ((size_t)(b * L_ + l) * T_ * T_) + ip;
    const float* fb = f + (size_t)b * T_ * E_ + e;
    float acc = 0.0f;
    #pragma unroll 4
    for (int j = 0; j < T_; ++j)
        acc = fmaf(ld1(G, gbase + (size_t)j * T_, bf), fb[(size_t)j * E_], acc);
    wgtb[i] = f2bfu(acc);
}

// ---------------- MFMA bf16 GEMM: Z[M,N] = A[M,K] * W[N,K]^T -------------
// MODE 0: gates   (Z -> gates f32 buffer at col zcolOff, + bias)
// MODE 1: head    (cols<2000 -> out; 2000/2001 -> stats; 2002.. -> p0b/p1b; LSE over cols<2002)
// MODE 2/3: tails (cols -> out at outColOff; LSE over all N)
template<int MODE>
__global__ void k_gemm(const unsigned short* __restrict__ A,
                       const unsigned short* __restrict__ Bw,
                       int M, int N, int K, int Nlse,
                       float* __restrict__ Zg, int zcolOff,
                       const void* __restrict__ bias, int biasOff,
                       void* __restrict__ out, int outColOff,
                       float* __restrict__ stats,
                       unsigned short* __restrict__ p0b,
                       unsigned short* __restrict__ p1b,
                       float* __restrict__ lsep, int slotBase,
                       const int* __restrict__ flagp) {
    const int bf = *flagp;
    const int bx = blockIdx.x, by = blockIdx.y;
    const int m0 = by * 128, n0 = bx * 128;
    const int t = threadIdx.x;
    const int wave = t >> 6, lane = t & 63;
    const int wm = wave >> 1, wn = wave & 1;
    const int quad = lane >> 4, l16 = lane & 15;

    __shared__ __align__(16) unsigned short As[128 * 40];
    __shared__ __align__(16) unsigned short Bs[128 * 40];
    __shared__ float pm[128][2], ps[128][2];

    float4v acc[4][4];
    #pragma unroll
    for (int mi = 0; mi < 4; ++mi)
        #pragma unroll
        for (int ni = 0; ni < 4; ++ni)
            acc[mi][ni] = (float4v){0.f, 0.f, 0.f, 0.f};

    for (int k0 = 0; k0 < K; k0 += 32) {
        if (k0) __syncthreads();
        #pragma unroll
        for (int i = 0; i < 2; ++i) {
            int idx = t + i * 256;
            int row = idx >> 2, seg = idx & 3;
            uint4 av = {0u, 0u, 0u, 0u};
            int gm = m0 + row;
            if (gm < M) av = *(const uint4*)(A + (size_t)gm * K + k0 + seg * 8);
            *(uint4*)(&As[row * 40 + seg * 8]) = av;
            uint4 bv = {0u, 0u, 0u, 0u};
            int gn = n0 + row;
            if (gn < N) bv = *(const uint4*)(Bw + (size_t)gn * K + k0 + seg * 8);
            *(uint4*)(&Bs[row * 40 + seg * 8]) = bv;
        }
        __syncthreads();
        short8v af[4], bfv[4];
        #pragma unroll
        for (int mi = 0; mi < 4; ++mi)
            af[mi] = *(const short8v*)(As + (wm * 64 + mi * 16 + l16) * 40 + quad * 8);
        #pragma unroll
        for (int ni = 0; ni < 4; ++ni)
            bfv[ni] = *(const short8v*)(Bs + (wn * 64 + ni * 16 + l16) * 40 + quad * 8);
        #pragma unroll
        for (int mi = 0; mi < 4; ++mi)
            #pragma unroll
            for (int ni = 0; ni < 4; ++ni)
                acc[mi][ni] = __builtin_amdgcn_mfma_f32_16x16x32_bf16(
                    af[mi], bfv[ni], acc[mi][ni], 0, 0, 0);
    }

    // ---- store epilogue ----
    #pragma unroll
    for (int mi = 0; mi < 4; ++mi) {
        #pragma unroll
        for (int r = 0; r < 4; ++r) {
            int grow = m0 + wm * 64 + mi * 16 + quad * 4 + r;
            if (grow >= M) continue;
            #pragma unroll
            for (int ni = 0; ni < 4; ++ni) {
                int gcol = n0 + wn * 64 + ni * 16 + l16;
                float v = acc[mi][ni][r];
                if (MODE == 0) {
                    if (gcol < N)
                        Zg[(size_t)grow * 3072 + zcolOff + gcol] =
                            v + ld1(bias, biasOff + gcol, bf);
                } else if (MODE == 1) {
                    if (gcol < C0_)        st1(out, (size_t)grow * V_ + gcol, bf, v);
                    else if (gcol < NH_)   stats[grow * 8 + 2 + (gcol - C0_)] = v;
                    else if (gcol < 2130)  p0b[grow * 128 + (gcol - NH_)] = f2bfu(v);
                    else if (gcol < NTOTC) p1b[grow * 32 + (gcol - 2130)] = f2bfu(v);
                } else {
                    if (gcol < N)
                        st1(out, (size_t)grow * V_ + outColOff + gcol, bf, v);
                }
            }
        }
    }

    // ---- fused per-tile LSE partials ----
    if (MODE != 0) {
        #pragma unroll
        for (int mi = 0; mi < 4; ++mi) {
            #pragma unroll
            for (int r = 0; r < 4; ++r) {
                float m = -1e30f, s = 0.0f;
                #pragma unroll
                for (int ni = 0; ni < 4; ++ni) {
                    int gcol = n0 + wn * 64 + ni * 16 + l16;
                    if (gcol < Nlse) lse_push(acc[mi][ni][r], m, s);
                }
                #pragma unroll
                for (int off = 1; off < 16; off <<= 1) {
                    float m2 = __shfl_xor(m, off), s2 = __shfl_xor(s, off);
                    lse_merge(m2, s2, m, s);
                }
                if (l16 == 0) {
                    int rl = wm * 64 + mi * 16 + quad * 4 + r;
                    pm[rl][wn] = m; ps[rl][wn] = s;
                }
            }
        }
        __syncthreads();
        if (t < 128) {
            int grow = m0 + t;
            if (grow < M) {
                float m = pm[t][0], s = ps[t][0];
                lse_merge(pm[t][1], ps[t][1], m, s);
                float* dst = lsep + ((size_t)grow * NSLOT + slotBase + bx) * 2;
                dst[0] = m; dst[1] = s;
            }
        }
    }
}

// ---------------- GRU pointwise ----------------
__device__ __forceinline__ float gru_out(const float* grow, int k, float h) {
    float i_r = grow[k], i_z = grow[512 + k], i_n = grow[1024 + k];
    float h_r = grow[1536 + k], h_z = grow[2048 + k], h_n = grow[2560 + k];
    float r = 1.0f / (1.0f + __expf(-(i_r + h_r)));
    float z = 1.0f / (1.0f + __expf(-(i_z + h_z)));
    float n = tanhf(i_n + r * h_n);
    return (1.0f - z) * n + z * h;
}

__global__ void k_apply_enc(const float* __restrict__ gates,
                            const float* __restrict__ hprev,
                            float* __restrict__ hnext,
                            unsigned short* __restrict__ hnextb) {
    int i = blockIdx.x * 256 + threadIdx.x;          // 262144
    int row = i >> 9, k = i & 511;
    float v = gru_out(gates + (size_t)row * 3072, k, hprev[i]);
    hnext[i] = v; hnextb[i] = f2bfu(v);
}

__global__ void k_h0(const float* __restrict__ ffin, float* __restrict__ hdec,
                     unsigned short* __restrict__ hdecb) {
    int i = blockIdx.x * 256 + threadIdx.x;          // 256000
    int row = i >> 9, e = i & 511;
    int b = row / NT_, t = row - b * NT_;
    float v = ffin[((size_t)(b * T_ + t) << 9) + e];
    hdec[i] = v; hdecb[i] = f2bfu(v);
}

__global__ void k_win(const float* __restrict__ embedded,
                      const int* __restrict__ lengths,
                      unsigned short* __restrict__ winb, int d) {
    int i = blockIdx.x * 256 + threadIdx.x;          // 256000
    int row = i >> 9, e = i & 511;
    int b = row / NT_, t = row - b * NT_;
    int tok = (d == 0 && t == 0) ? (lengths[b] - 1) : (t + d - 1);
    winb[i] = f2bfu(embedded[((size_t)(b * T_ + tok) << 9) + e]);
}

__global__ void k_apply_dec(const float* __restrict__ gates,
                            float* __restrict__ hdec,
                            unsigned short* __restrict__ hdecb,
                            unsigned short* __restrict__ hsb,
                            const int* __restrict__ lengths, int d) {
    int i = blockIdx.x * 256 + threadIdx.x;          // 256000
    int row = i >> 9, k = i & 511;
    int b = row / NT_, t = row - b * NT_;
    float hn = gru_out(gates + (size_t)row * 3072, k, hdec[i]);
    hdec[i] = hn; hdecb[i] = f2bfu(hn);
    bool valid = (t + d) < lengths[b];
    hsb[(((size_t)row * D_ + d) << 9) + k] = valid ? f2bfu(hn) : (unsigned short)0;
}

// ---------------- combine LSE partials -> per-row corrections ----------------
__global__ void k_corr2(const float* __restrict__ lsep, const float* __restrict__ stats,
                        float* __restrict__ corr) {
    int r = blockIdx.x * 256 + threadIdx.x;
    if (r >= NROW_) return;
    const float* P = lsep + (size_t)r * NSLOT * 2;
    float m = -1e30f, s = 0.0f;
    for (int i = 0; i < 17; ++i)  lse_merge(P[2 * i], P[2 * i + 1], m, s);
    float ch = m + logf(s);
    float lp0 = stats[r * 8 + 2] - ch;
    float lp1 = stats[r * 8 + 3] - ch;
    m = -1e30f; s = 0.0f;
    for (int i = 17; i < 80; ++i) lse_merge(P[2 * i], P[2 * i + 1], m, s);
    float ct0 = m + logf(s);
    m = -1e30f; s = 0.0f;
    for (int i = 80; i < 252; ++i) lse_merge(P[2 * i], P[2 * i + 1], m, s);
    float ct1 = m + logf(s);
    corr[r * 4 + 0] = ch;
    corr[r * 4 + 1] = ct0 - lp0;
    corr[r * 4 + 2] = ct1 - lp1;
}

// ---------------- final: out = z - corr, zero invalid rows ----------------
__global__ void k_final(void* __restrict__ out, const float* __restrict__ corr,
                        const int* __restrict__ lengths, const int* __restrict__ flagp) {
    const int bf = *flagp;
    size_t vec = (size_t)blockIdx.x * 256 + threadIdx.x;   // 8,000,000 vecs of 8
    size_t base = vec << 3;
    int r = (int)(base / V_);
    int c = (int)(base - (size_t)r * V_);
    int b = r / 500;
    int t = (r - b * 500) >> 2;
    if (t >= lengths[b]) {
        if (bf) { uint4 z = {0u,0u,0u,0u}; *(uint4*)((unsigned short*)out + base) = z; }
        else { float4 z = {0.f,0.f,0.f,0.f};
               float4* p = (float4*)((float*)out + base); p[0] = z; p[1] = z; }
        return;
    }
    float cr = (c < C0_) ? corr[r * 4 + 0] : ((c < C1_) ? corr[r * 4 + 1] : corr[r * 4 + 2]);
    if (bf) {
        uint4 u = *(const uint4*)((const unsigned short*)out + base);
        unsigned us[8] = {u.x & 0xffffu, u.x >> 16, u.y & 0xffffu, u.y >> 16,
                          u.z & 0xffffu, u.z >> 16, u.w & 0xffffu, u.w >> 16};
        unsigned short o[8];
        #pragma unroll
        for (int q = 0; q < 8; ++q)
            o[q] = f2bfu(ubf2f((unsigned short)us[q]) - cr);
        uint4 w;
        w.x = (unsigned)o[0] | ((unsigned)o[1] << 16);
        w.y = (unsigned)o[2] | ((unsigned)o[3] << 16);
        w.z = (unsigned)o[4] | ((unsigned)o[5] << 16);
        w.w = (unsigned)o[6] | ((unsigned)o[7] << 16);
        *(uint4*)((unsigned short*)out + base) = w;
    } else {
        float4* p = (float4*)((float*)out + base);
        float4 a0 = p[0], a1 = p[1];
        a0.x -= cr; a0.y -= cr; a0.z -= cr; a0.w -= cr;
        a1.x -= cr; a1.y -= cr; a1.z -= cr; a1.w -= cr;
        p[0] = a0; p[1] = a1;
    }
}

// ---------------- workspace layout (float offsets, all 16B aligned) -------
#define OFF_EMB    0u          // 262144 f32
#define OFF_FA     262144u     // 262144 f32
#define OFF_FB     524288u     // 262144 f32
#define OFF_FAB    786432u     // 262144 bf16 = 131072 fl
#define OFF_FBB    917504u     // 131072 fl
#define OFF_WGTB   1048576u    // 131072 fl
#define OFF_GATES  1179648u    // 512*3072 f32 = 1572864 fl
#define OFF_HDEC   2752512u    // 256000 f32
#define OFF_HDECB  3008512u    // 128000 fl
#define OFF_WINB   3136512u    // 128000 fl
#define OFF_HSB    3264512u    // 2000*512 bf16 = 512000 fl
#define OFF_P0B    3776512u    // 128000 fl
#define OFF_P1B    3904512u    // 32000 fl
#define OFF_STATS  3936512u    // 16000 fl
#define OFF_CORR   3952512u    // 8000 fl
#define OFF_LSEP   3960512u    // 2000*252*2 = 1008000 fl
#define OFF_WB     4968512u    // 7553504 bf16 = 3776752 fl
#define OFF_FLAG   8745264u

// bf16 weight region sub-offsets (in shorts)
#define WO_ENCIH   0u
#define WO_ENCHH   1572864u
#define WO_DECIH   3145728u
#define WO_DECHH   3932160u
#define WO_W1      4718592u    // head_w rows, then t0_proj, then t1_proj (2162x512)
#define WO_T0O     5825536u    // 8000x128
#define WO_T1O     6849536u    // 22000x32
#define WO_END     7553504u

extern "C" void kernel_launch(void* const* d_in, const int* in_sizes, int n_in,
                              void* d_out, int out_size, void* d_ws, size_t ws_size,
                              hipStream_t stream) {
    (void)in_sizes; (void)n_in; (void)out_size; (void)ws_size;
    const int*  x        = (const int*)d_in[0];
    const int*  lengths  = (const int*)d_in[1];
    const void* G        = d_in[2];
    const void* emb      = d_in[3];
    const void* enc_w_ih = d_in[4];
    const void* enc_w_hh = d_in[5];
    const void* enc_b_ih = d_in[6];
    const void* enc_b_hh = d_in[7];
    const void* dec_w_ih = d_in[8];
    const void* dec_w_hh = d_in[9];
    const void* dec_b_ih = d_in[10];
    const void* dec_b_hh = d_in[11];
    const void* head_w   = d_in[12];
    const void* t0_proj  = d_in[13];
    const void* t0_out   = d_in[14];
    const void* t1_proj  = d_in[15];
    const void* t1_out   = d_in[16];

    float* ws = (float*)d_ws;
    float* embedded = ws + OFF_EMB;
    float* fA    = ws + OFF_FA;
    float* fB    = ws + OFF_FB;
    unsigned short* fAb  = (unsigned short*)(ws + OFF_FAB);
    unsigned short* fBb  = (unsigned short*)(ws + OFF_FBB);
    unsigned short* wgtb = (unsigned short*)(ws + OFF_WGTB);
    float* gates = ws + OFF_GATES;
    float* hdec  = ws + OFF_HDEC;
    unsigned short* hdecb = (unsigned short*)(ws + OFF_HDECB);
    unsigned short* winb  = (unsigned short*)(ws + OFF_WINB);
    unsigned short* hsb   = (unsigned short*)(ws + OFF_HSB);
    unsigned short* p0b   = (unsigned short*)(ws + OFF_P0B);
    unsigned short* p1b   = (unsigned short*)(ws + OFF_P1B);
    float* stats = ws + OFF_STATS;
    float* corr  = ws + OFF_CORR;
    float* lsep  = ws + OFF_LSEP;
    unsigned short* WB = (unsigned short*)(ws + OFF_WB);
    int* flagp = (int*)(ws + OFF_FLAG);
    void* out = d_out;

    k_detect<<<1, 64, 0, stream>>>(G, flagp);

    ConvArgs ca;
    ca.src[0] = enc_w_ih; ca.src[1] = enc_w_hh; ca.src[2] = dec_w_ih;
    ca.src[3] = dec_w_hh; ca.src[4] = head_w;   ca.src[5] = t0_proj;
    ca.src[6] = t1_proj;  ca.src[7] = t0_out;   ca.src[8] = t1_out;
    ca.off[0] = WO_ENCIH; ca.off[1] = WO_ENCHH; ca.off[2] = WO_DECIH;
    ca.off[3] = WO_DECHH; ca.off[4] = WO_W1;
    ca.off[5] = WO_W1 + 2002u * 512u;   // t0_proj rows
    ca.off[6] = WO_W1 + 2130u * 512u;   // t1_proj rows
    ca.off[7] = WO_T0O;   ca.off[8] = WO_T1O;   ca.off[9] = WO_END;
    k_wconv<<<4096, 256, 0, stream>>>(ca, WB, flagp);

    k_embed<<<1024, 256, 0, stream>>>(x, emb, embedded, fA, fAb, flagp);

    // encoder layer 0: fA -> fB
    k_wgt<<<1024, 256, 0, stream>>>(G, fA, wgtb, 0, flagp);
    k_gemm<0><<<dim3(12, 4), 256, 0, stream>>>(wgtb, WB + WO_ENCIH, 512, 1536, 512, 0,
        gates, 0, enc_b_ih, 0, nullptr, 0, nullptr, nullptr, nullptr, nullptr, 0, flagp);
    k_gemm<0><<<dim3(12, 4), 256, 0, stream>>>(fAb, WB + WO_ENCHH, 512, 1536, 512, 0,
        gates, 1536, enc_b_hh, 0, nullptr, 0, nullptr, nullptr, nullptr, nullptr, 0, flagp);
    k_apply_enc<<<1024, 256, 0, stream>>>(gates, fA, fB, fBb);

    // encoder layer 1: fB -> fA
    k_wgt<<<1024, 256, 0, stream>>>(G, fB, wgtb, 1, flagp);
    k_gemm<0><<<dim3(12, 4), 256, 0, stream>>>(wgtb, WB + WO_ENCIH + 786432u, 512, 1536, 512, 0,
        gates, 0, enc_b_ih, 1536, nullptr, 0, nullptr, nullptr, nullptr, nullptr, 0, flagp);
    k_gemm<0><<<dim3(12, 4), 256, 0, stream>>>(fBb, WB + WO_ENCHH + 786432u, 512, 1536, 512, 0,
        gates, 1536, enc_b_hh, 1536, nullptr, 0, nullptr, nullptr, nullptr, nullptr, 0, flagp);
    k_apply_enc<<<1024, 256, 0, stream>>>(gates, fB, fA, fAb);

    // decoder
    k_h0<<<1000, 256, 0, stream>>>(fA, hdec, hdecb);
    for (int d = 0; d < D_; ++d) {
        k_win<<<1000, 256, 0, stream>>>(embedded, lengths, winb, d);
        k_gemm<0><<<dim3(12, 4), 256, 0, stream>>>(winb, WB + WO_DECIH, 500, 1536, 512, 0,
            gates, 0, dec_b_ih, 0, nullptr, 0, nullptr, nullptr, nullptr, nullptr, 0, flagp);
        k_gemm<0><<<dim3(12, 4), 256, 0, stream>>>(hdecb, WB + WO_DECHH, 500, 1536, 512, 0,
            gates, 1536, dec_b_hh, 0, nullptr, 0, nullptr, nullptr, nullptr, nullptr, 0, flagp);
        k_apply_dec<<<1000, 256, 0, stream>>>(gates, hdec, hdecb, hsb, lengths, d);
    }

    // adaptive softmax logits
    k_gemm<1><<<dim3(17, 16), 256, 0, stream>>>(hsb, WB + WO_W1, NROW_, NTOTC, 512, NH_,
        nullptr, 0, nullptr, 0, out, 0, stats, p0b, p1b, lsep, 0, flagp);
    k_gemm<2><<<dim3(63, 16), 256, 0, stream>>>(p0b, WB + WO_T0O, NROW_, 8000, 128, 8000,
        nullptr, 0, nullptr, 0, out, C0_, stats, nullptr, nullptr, lsep, 17, flagp);
    k_gemm<3><<<dim3(172, 16), 256, 0, stream>>>(p1b, WB + WO_T1O, NROW_, 22000, 32, 22000,
        nullptr, 0, nullptr, 0, out, C1_, stats, nullptr, nullptr, lsep, 80, flagp);

    k_corr2<<<8, 256, 0, stream>>>(lsep, stats, corr);
    k_final<<<31250, 256, 0, stream>>>(out, corr, lengths, flagp);
}

// Round 4
// 799.785 us; speedup vs baseline: 10.8884x; 1.1571x over previous
//
#include <hip/hip_runtime.h>
#include <hip/hip_bf16.h>

typedef __hip_bfloat16 bf16;
typedef __attribute__((ext_vector_type(8))) short short8v;
typedef __attribute__((ext_vector_type(4))) float float4v;

#define V_    32000
#define E_    512
#define H_    512
#define T_    128
#define B_    4
#define D_    4
#define L_    2
#define C0_   2000
#define C1_   10000
#define NT_   125
#define NROW_ 2000          // B*NT*D
#define NH_   2002
#define NTOTC 2162          // 2002 + 128 + 32
#define NSLOT 252           // 17 head + 63 t0 + 172 t1 LSE partial slots per row

__device__ __forceinline__ float bf2f(bf16 v) { return __bfloat162float(v); }
__device__ __forceinline__ unsigned short f2bfu(float f) {
    bf16 h = __float2bfloat16(f);
    union { bf16 h; unsigned short u; } cv; cv.h = h; return cv.u;
}
// dtype-flag helpers: bf==1 -> bf16 input data, bf==0 -> float32
__device__ __forceinline__ float ld1(const void* p, size_t i, int bf) {
    return bf ? bf2f(((const bf16*)p)[i]) : ((const float*)p)[i];
}
__device__ __forceinline__ void st1(void* p, size_t i, int bf, float v) {
    if (bf) ((unsigned short*)p)[i] = f2bfu(v);
    else    ((float*)p)[i] = v;
}

__device__ __forceinline__ void lse_push(float z, float& m, float& s) {
    if (z <= m) { s += __expf(z - m); }
    else        { s = s * __expf(m - z) + 1.0f; m = z; }
}
__device__ __forceinline__ void lse_merge(float m2, float s2, float& m, float& s) {
    float mm = fmaxf(m, m2);
    s = s * __expf(m - mm) + s2 * __expf(m2 - mm);
    m = mm;
}

// ---------------- stage 0: dtype detect (G row 0 is a softmax row) --------
__global__ void k_detect(const void* __restrict__ G, int* __restrict__ flag) {
    int t = threadIdx.x;   // 64 threads
    float s32 = 0.0f;
    for (int k = t; k < 128; k += 64) s32 += ((const float*)G)[k];
    for (int off = 32; off; off >>= 1) s32 += __shfl_down(s32, off);
    if (t == 0) {
        float e32 = fabsf(s32 - 1.0f);
        *flag = (e32 < 0.05f) ? 0 : 1;   // NaN compares false -> bf16 fallback
    }
}

// ---------------- weight conversion -> one contiguous bf16 region ---------
struct ConvArgs {
    const void* src[9];
    unsigned int off[10];
};
__global__ void k_wconv(ConvArgs a, unsigned short* __restrict__ wb,
                        const int* __restrict__ flagp) {
    const int bf = *flagp;
    unsigned int total = a.off[9];
    for (unsigned int i = blockIdx.x * 256 + threadIdx.x; i < total;
         i += gridDim.x * 256) {
        int seg = 0;
        while (i >= a.off[seg + 1]) seg++;
        wb[i] = f2bfu(ld1(a.src[seg], i - a.off[seg], bf));
    }
}

// ---------------- embedding gather ----------------
__global__ void k_embed(const int* __restrict__ x, const void* __restrict__ emb,
                        float* __restrict__ embedded, float* __restrict__ f0,
                        unsigned short* __restrict__ f0b,
                        const int* __restrict__ flagp) {
    const int bf = *flagp;
    int i = blockIdx.x * 256 + threadIdx.x;          // 262144
    int bt = i >> 9, e = i & 511;
    int tok = x[bt];
    float v = ld1(emb, (size_t)tok * E_ + e, bf);
    embedded[i] = v; f0[i] = v; f0b[i] = f2bfu(v);
}

// ---------------- wgt[b,i,e] = sum_j G[b,l,j,i] f[b,j,e] ------------------
__global__ void k_wgt(const void* __restrict__ G, const float* __restrict__ f,
                      unsigned short* __restrict__ wgtb, int l,
                      const int* __restrict__ flagp) {
    const int bf = *flagp;
    int i = blockIdx.x * 256 + threadIdx.x;          // 262144
    int e = i & 511;
    int bi = i >> 9;
    int b = bi >> 7, ip = bi & 127;
    size_t gbase = ((size_t)(b * L_ + l) * T_ * T_) + ip;
    const float* fb = f + (size_t)b * T_ * E_ + e;
    float acc = 0.0f;
    #pragma unroll 4
    for (int j = 0; j < T_; ++j)
        acc = fmaf(ld1(G, gbase + (size_t)j * T_, bf), fb[(size_t)j * E_], acc);
    wgtb[i] = f2bfu(acc);
}

// ---------------- MFMA bf16 GEMM: Z[M,N] = A[M,K] * W[N,K]^T --------------
// MODE 0: gates   (store Z+bias into Zg at col z*zcol1; blockIdx.z picks A/W/bias)
// MODE 1: head passA (LSE cols<2002 -> lsep; stats 2000/2001; proj -> p0b/p1b)
// MODE 2: tail passA (LSE over all N -> lsep at slotBase)
// MODE 3/4/5: passB (store valid ? z - corr[crIdx] : 0 into out at outColOff)
struct GemmP {
    const unsigned short* A0;
    const unsigned short* A1;
    const unsigned short* W;
    unsigned long long w1off;
    int M, N, K, Nlse;
    float* Zg; int ldz; int zcol1;
    const void* bias0; const void* bias1; int boff;
    void* out; int outColOff;
    float* stats;
    unsigned short* p0b;
    unsigned short* p1b;
    float* lsep; int slotBase;
    const float* corr;
    const int* lengths;
    const int* flagp;
};

template<int MODE>
__global__ void k_gemm(GemmP p) {
    const int bf = *p.flagp;
    const int zsel = blockIdx.z;
    const unsigned short* A  = zsel ? p.A1 : p.A0;
    const unsigned short* Bw = p.W + (zsel ? p.w1off : 0ull);
    const int M = p.M, N = p.N, K = p.K;
    const int bx = blockIdx.x, by = blockIdx.y;
    const int m0 = by * 128, n0 = bx * 128;
    const int t = threadIdx.x;
    const int wave = t >> 6, lane = t & 63;
    const int wm = wave >> 1, wn = wave & 1;
    const int quad = lane >> 4, l16 = lane & 15;

    __shared__ __align__(16) unsigned short As[128 * 40];
    __shared__ __align__(16) unsigned short Bs[128 * 40];
    __shared__ float pm[128][2], ps[128][2];

    float4v acc[4][4];
    #pragma unroll
    for (int mi = 0; mi < 4; ++mi)
        #pragma unroll
        for (int ni = 0; ni < 4; ++ni)
            acc[mi][ni] = (float4v){0.f, 0.f, 0.f, 0.f};

    for (int k0 = 0; k0 < K; k0 += 32) {
        if (k0) __syncthreads();
        #pragma unroll
        for (int i = 0; i < 2; ++i) {
            int idx = t + i * 256;
            int row = idx >> 2, seg = idx & 3;
            uint4 av = {0u, 0u, 0u, 0u};
            int gm = m0 + row;
            if (gm < M) av = *(const uint4*)(A + (size_t)gm * K + k0 + seg * 8);
            *(uint4*)(&As[row * 40 + seg * 8]) = av;
            uint4 bv = {0u, 0u, 0u, 0u};
            int gn = n0 + row;
            if (gn < N) bv = *(const uint4*)(Bw + (size_t)gn * K + k0 + seg * 8);
            *(uint4*)(&Bs[row * 40 + seg * 8]) = bv;
        }
        __syncthreads();
        short8v af[4], bfv[4];
        #pragma unroll
        for (int mi = 0; mi < 4; ++mi)
            af[mi] = *(const short8v*)(As + (wm * 64 + mi * 16 + l16) * 40 + quad * 8);
        #pragma unroll
        for (int ni = 0; ni < 4; ++ni)
            bfv[ni] = *(const short8v*)(Bs + (wn * 64 + ni * 16 + l16) * 40 + quad * 8);
        #pragma unroll
        for (int mi = 0; mi < 4; ++mi)
            #pragma unroll
            for (int ni = 0; ni < 4; ++ni)
                acc[mi][ni] = __builtin_amdgcn_mfma_f32_16x16x32_bf16(
                    af[mi], bfv[ni], acc[mi][ni], 0, 0, 0);
    }

    // ---- epilogue ----
    if (MODE == 0) {
        const void* bias = zsel ? p.bias1 : p.bias0;
        const int zcol = zsel ? p.zcol1 : 0;
        #pragma unroll
        for (int mi = 0; mi < 4; ++mi)
            #pragma unroll
            for (int r = 0; r < 4; ++r) {
                int grow = m0 + wm * 64 + mi * 16 + quad * 4 + r;
                if (grow >= M) continue;
                #pragma unroll
                for (int ni = 0; ni < 4; ++ni) {
                    int gcol = n0 + wn * 64 + ni * 16 + l16;
                    if (gcol < N)
                        p.Zg[(size_t)grow * p.ldz + zcol + gcol] =
                            acc[mi][ni][r] + ld1(bias, p.boff + gcol, bf);
                }
            }
    } else if (MODE == 1) {
        #pragma unroll
        for (int mi = 0; mi < 4; ++mi)
            #pragma unroll
            for (int r = 0; r < 4; ++r) {
                int grow = m0 + wm * 64 + mi * 16 + quad * 4 + r;
                if (grow >= M) continue;
                #pragma unroll
                for (int ni = 0; ni < 4; ++ni) {
                    int gcol = n0 + wn * 64 + ni * 16 + l16;
                    float v = acc[mi][ni][r];
                    if (gcol >= C0_ && gcol < NH_) p.stats[grow * 8 + 2 + (gcol - C0_)] = v;
                    else if (gcol >= NH_ && gcol < 2130) p.p0b[grow * 128 + (gcol - NH_)] = f2bfu(v);
                    else if (gcol >= 2130 && gcol < NTOTC) p.p1b[grow * 32 + (gcol - 2130)] = f2bfu(v);
                }
            }
    } else if (MODE >= 3) {
        const int crIdx = MODE - 3;
        #pragma unroll
        for (int mi = 0; mi < 4; ++mi)
            #pragma unroll
            for (int r = 0; r < 4; ++r) {
                int grow = m0 + wm * 64 + mi * 16 + quad * 4 + r;
                if (grow >= M) continue;
                int b = grow / 500;
                int tt = (grow - b * 500) >> 2;
                bool valid = tt < p.lengths[b];
                float cr = p.corr[grow * 4 + crIdx];
                #pragma unroll
                for (int ni = 0; ni < 4; ++ni) {
                    int gcol = n0 + wn * 64 + ni * 16 + l16;
                    if (gcol < N) {
                        float v = valid ? (acc[mi][ni][r] - cr) : 0.0f;
                        st1(p.out, (size_t)grow * V_ + p.outColOff + gcol, bf, v);
                    }
                }
            }
    }

    // ---- fused per-tile LSE partials (pass A modes only) ----
    if (MODE == 1 || MODE == 2) {
        const int Nlse = p.Nlse;
        #pragma unroll
        for (int mi = 0; mi < 4; ++mi) {
            #pragma unroll
            for (int r = 0; r < 4; ++r) {
                float m = -1e30f, s = 0.0f;
                #pragma unroll
                for (int ni = 0; ni < 4; ++ni) {
                    int gcol = n0 + wn * 64 + ni * 16 + l16;
                    if (gcol < Nlse) lse_push(acc[mi][ni][r], m, s);
                }
                #pragma unroll
                for (int off = 1; off < 16; off <<= 1) {
                    float m2 = __shfl_xor(m, off), s2 = __shfl_xor(s, off);
                    lse_merge(m2, s2, m, s);
                }
                if (l16 == 0) {
                    int rl = wm * 64 + mi * 16 + quad * 4 + r;
                    pm[rl][wn] = m; ps[rl][wn] = s;
                }
            }
        }
        __syncthreads();
        if (t < 128) {
            int grow = m0 + t;
            if (grow < M) {
                float m = pm[t][0], s = ps[t][0];
                lse_merge(pm[t][1], ps[t][1], m, s);
                float* dst = p.lsep + ((size_t)grow * NSLOT + p.slotBase + bx) * 2;
                dst[0] = m; dst[1] = s;
            }
        }
    }
}

// ---------------- GRU pointwise ----------------
__device__ __forceinline__ float gru2(float i_r, float i_z, float i_n,
                                      float h_r, float h_z, float h_n, float h) {
    float r = 1.0f / (1.0f + __expf(-(i_r + h_r)));
    float z = 1.0f / (1.0f + __expf(-(i_z + h_z)));
    float n = tanhf(i_n + r * h_n);
    return (1.0f - z) * n + z * h;
}

__global__ void k_apply_enc(const float* __restrict__ gates,
                            const float* __restrict__ hprev,
                            float* __restrict__ hnext,
                            unsigned short* __restrict__ hnextb) {
    int i = blockIdx.x * 256 + threadIdx.x;          // 262144
    int row = i >> 9, k = i & 511;
    const float* g = gates + (size_t)row * 3072;
    float v = gru2(g[k], g[512 + k], g[1024 + k],
                   g[1536 + k], g[2048 + k], g[2560 + k], hprev[i]);
    hnext[i] = v; hnextb[i] = f2bfu(v);
}

__global__ void k_h0(const float* __restrict__ ffin, float* __restrict__ hdec,
                     unsigned short* __restrict__ hdecb) {
    int i = blockIdx.x * 256 + threadIdx.x;          // 256000
    int row = i >> 9, e = i & 511;
    int b = row / NT_, t = row - b * NT_;
    float v = ffin[((size_t)(b * T_ + t) << 9) + e];
    hdec[i] = v; hdecb[i] = f2bfu(v);
}

// all 4 window slices at once: wr = d*500 + (b*125 + t)
__global__ void k_winall(const float* __restrict__ embedded,
                         const int* __restrict__ lengths,
                         unsigned short* __restrict__ winb) {
    int i = blockIdx.x * 256 + threadIdx.x;          // 1,024,000
    int e = i & 511;
    int wr = i >> 9;
    int d = wr / 500, row = wr - d * 500;
    int b = row / NT_, t = row - b * NT_;
    int tok = (d == 0 && t == 0) ? (lengths[b] - 1) : (t + d - 1);
    winb[i] = f2bfu(embedded[((size_t)(b * T_ + tok) << 9) + e]);
}

__global__ void k_apply_dec(const float* __restrict__ gih,
                            const float* __restrict__ ghh,
                            float* __restrict__ hdec,
                            unsigned short* __restrict__ hdecb,
                            unsigned short* __restrict__ hsb,
                            const int* __restrict__ lengths, int d) {
    int i = blockIdx.x * 256 + threadIdx.x;          // 256000
    int row = i >> 9, k = i & 511;
    int b = row / NT_, t = row - b * NT_;
    const float* gi = gih + (size_t)(d * 500 + row) * 1536;
    const float* gh = ghh + (size_t)row * 1536;
    float hn = gru2(gi[k], gi[512 + k], gi[1024 + k],
                    gh[k], gh[512 + k], gh[1024 + k], hdec[i]);
    hdec[i] = hn; hdecb[i] = f2bfu(hn);
    bool valid = (t + d) < lengths[b];
    hsb[(((size_t)row * D_ + d) << 9) + k] = valid ? f2bfu(hn) : (unsigned short)0;
}

// ---------------- combine LSE partials -> per-row corrections -------------
__global__ void k_corr2(const float* __restrict__ lsep, const float* __restrict__ stats,
                        float* __restrict__ corr) {
    int r = blockIdx.x * 256 + threadIdx.x;
    if (r >= NROW_) return;
    const float* P = lsep + (size_t)r * NSLOT * 2;
    float m = -1e30f, s = 0.0f;
    for (int i = 0; i < 17; ++i)  lse_merge(P[2 * i], P[2 * i + 1], m, s);
    float ch = m + logf(s);
    float lp0 = stats[r * 8 + 2] - ch;
    float lp1 = stats[r * 8 + 3] - ch;
    m = -1e30f; s = 0.0f;
    for (int i = 17; i < 80; ++i) lse_merge(P[2 * i], P[2 * i + 1], m, s);
    float ct0 = m + logf(s);
    m = -1e30f; s = 0.0f;
    for (int i = 80; i < 252; ++i) lse_merge(P[2 * i], P[2 * i + 1], m, s);
    float ct1 = m + logf(s);
    corr[r * 4 + 0] = ch;
    corr[r * 4 + 1] = ct0 - lp0;
    corr[r * 4 + 2] = ct1 - lp1;
}

// ---------------- workspace layout (float offsets, 16B aligned) -----------
#define OFF_EMB    0u          // 262144
#define OFF_FA     262144u     // 262144
#define OFF_FB     524288u     // 262144
#define OFF_FAB    786432u     // 131072 (262144 bf16)
#define OFF_FBB    917504u     // 131072
#define OFF_WGTB   1048576u    // 131072
#define OFF_GATES  1179648u    // 512*3072 = 1572864
#define OFF_GIH    2752512u    // 2000*1536 = 3072000
#define OFF_GHH    5824512u    // 500*1536 = 768000
#define OFF_HDEC   6592512u    // 256000
#define OFF_HDECB  6848512u    // 128000
#define OFF_WINB   6976512u    // 512000 (1,024,000 bf16)
#define OFF_HSB    7488512u    // 512000 (1,024,000 bf16)
#define OFF_P0B    8000512u    // 128000 (256000 bf16)
#define OFF_P1B    8128512u    // 32000  (64000 bf16)
#define OFF_STATS  8160512u    // 16000
#define OFF_CORR   8176512u    // 8000
#define OFF_LSEP   8184512u    // 1008000
#define OFF_WB     9192512u    // 3776752 (7553504 bf16)
#define OFF_FLAG   12969264u

// bf16 weight region sub-offsets (shorts)
#define WO_ENCIH   0u
#define WO_ENCHH   1572864u
#define WO_DECIH   3145728u
#define WO_DECHH   3932160u
#define WO_W1      4718592u    // head_w rows, t0_proj, t1_proj (2162x512)
#define WO_T0O     5825536u    // 8000x128
#define WO_T1O     6849536u    // 22000x32
#define WO_END     7553504u

static inline GemmP mkp(const unsigned short* A0, const unsigned short* A1,
                        const unsigned short* W, unsigned long long w1off,
                        int M, int N, int K, int Nlse,
                        float* Zg, int ldz, int zcol1,
                        const void* bias0, const void* bias1, int boff,
                        void* out, int outColOff, float* stats,
                        unsigned short* p0b, unsigned short* p1b,
                        float* lsep, int slotBase, const float* corr,
                        const int* lengths, const int* flagp) {
    GemmP p;
    p.A0 = A0; p.A1 = A1; p.W = W; p.w1off = w1off;
    p.M = M; p.N = N; p.K = K; p.Nlse = Nlse;
    p.Zg = Zg; p.ldz = ldz; p.zcol1 = zcol1;
    p.bias0 = bias0; p.bias1 = bias1; p.boff = boff;
    p.out = out; p.outColOff = outColOff; p.stats = stats;
    p.p0b = p0b; p.p1b = p1b; p.lsep = lsep; p.slotBase = slotBase;
    p.corr = corr; p.lengths = lengths; p.flagp = flagp;
    return p;
}

extern "C" void kernel_launch(void* const* d_in, const int* in_sizes, int n_in,
                              void* d_out, int out_size, void* d_ws, size_t ws_size,
                              hipStream_t stream) {
    (void)in_sizes; (void)n_in; (void)out_size; (void)ws_size;
    const int*  x        = (const int*)d_in[0];
    const int*  lengths  = (const int*)d_in[1];
    const void* G        = d_in[2];
    const void* emb      = d_in[3];
    const void* enc_w_ih = d_in[4];
    const void* enc_w_hh = d_in[5];
    const void* enc_b_ih = d_in[6];
    const void* enc_b_hh = d_in[7];
    const void* dec_w_ih = d_in[8];
    const void* dec_w_hh = d_in[9];
    const void* dec_b_ih = d_in[10];
    const void* dec_b_hh = d_in[11];
    const void* head_w   = d_in[12];
    const void* t0_proj  = d_in[13];
    const void* t0_out   = d_in[14];
    const void* t1_proj  = d_in[15];
    const void* t1_out   = d_in[16];

    float* ws = (float*)d_ws;
    float* embedded = ws + OFF_EMB;
    float* fA    = ws + OFF_FA;
    float* fB    = ws + OFF_FB;
    unsigned short* fAb  = (unsigned short*)(ws + OFF_FAB);
    unsigned short* fBb  = (unsigned short*)(ws + OFF_FBB);
    unsigned short* wgtb = (unsigned short*)(ws + OFF_WGTB);
    float* gates = ws + OFF_GATES;
    float* gih   = ws + OFF_GIH;
    float* ghh   = ws + OFF_GHH;
    float* hdec  = ws + OFF_HDEC;
    unsigned short* hdecb = (unsigned short*)(ws + OFF_HDECB);
    unsigned short* winb  = (unsigned short*)(ws + OFF_WINB);
    unsigned short* hsb   = (unsigned short*)(ws + OFF_HSB);
    unsigned short* p0b   = (unsigned short*)(ws + OFF_P0B);
    unsigned short* p1b   = (unsigned short*)(ws + OFF_P1B);
    float* stats = ws + OFF_STATS;
    float* corr  = ws + OFF_CORR;
    float* lsep  = ws + OFF_LSEP;
    unsigned short* WB = (unsigned short*)(ws + OFF_WB);
    int* flagp = (int*)(ws + OFF_FLAG);
    void* out = d_out;

    k_detect<<<1, 64, 0, stream>>>(G, flagp);

    ConvArgs ca;
    ca.src[0] = enc_w_ih; ca.src[1] = enc_w_hh; ca.src[2] = dec_w_ih;
    ca.src[3] = dec_w_hh; ca.src[4] = head_w;   ca.src[5] = t0_proj;
    ca.src[6] = t1_proj;  ca.src[7] = t0_out;   ca.src[8] = t1_out;
    ca.off[0] = WO_ENCIH; ca.off[1] = WO_ENCHH; ca.off[2] = WO_DECIH;
    ca.off[3] = WO_DECHH; ca.off[4] = WO_W1;
    ca.off[5] = WO_W1 + 2002u * 512u;
    ca.off[6] = WO_W1 + 2130u * 512u;
    ca.off[7] = WO_T0O;   ca.off[8] = WO_T1O;   ca.off[9] = WO_END;
    k_wconv<<<4096, 256, 0, stream>>>(ca, WB, flagp);

    k_embed<<<1024, 256, 0, stream>>>(x, emb, embedded, fA, fAb, flagp);

    // encoder layer 0: fA -> fB  (ih + hh fused via gridDim.z)
    k_wgt<<<1024, 256, 0, stream>>>(G, fA, wgtb, 0, flagp);
    k_gemm<0><<<dim3(12, 4, 2), 256, 0, stream>>>(mkp(
        wgtb, fAb, WB + WO_ENCIH, (unsigned long long)(WO_ENCHH - WO_ENCIH),
        512, 1536, 512, 0, gates, 3072, 1536, enc_b_ih, enc_b_hh, 0,
        nullptr, 0, nullptr, nullptr, nullptr, nullptr, 0, nullptr, lengths, flagp));
    k_apply_enc<<<1024, 256, 0, stream>>>(gates, fA, fB, fBb);

    // encoder layer 1: fB -> fA
    k_wgt<<<1024, 256, 0, stream>>>(G, fB, wgtb, 1, flagp);
    k_gemm<0><<<dim3(12, 4, 2), 256, 0, stream>>>(mkp(
        wgtb, fBb, WB + WO_ENCIH + 786432u, (unsigned long long)(WO_ENCHH - WO_ENCIH),
        512, 1536, 512, 0, gates, 3072, 1536, enc_b_ih, enc_b_hh, 1536,
        nullptr, 0, nullptr, nullptr, nullptr, nullptr, 0, nullptr, lengths, flagp));
    k_apply_enc<<<1024, 256, 0, stream>>>(gates, fB, fA, fAb);

    // decoder: batched window gather + batched ih GEMM, serial hh
    k_h0<<<1000, 256, 0, stream>>>(fA, hdec, hdecb);
    k_winall<<<4000, 256, 0, stream>>>(embedded, lengths, winb);
    k_gemm<0><<<dim3(12, 16, 1), 256, 0, stream>>>(mkp(
        winb, nullptr, WB + WO_DECIH, 0ull, 2000, 1536, 512, 0,
        gih, 1536, 0, dec_b_ih, nullptr, 0,
        nullptr, 0, nullptr, nullptr, nullptr, nullptr, 0, nullptr, lengths, flagp));
    for (int d = 0; d < D_; ++d) {
        k_gemm<0><<<dim3(12, 4, 1), 256, 0, stream>>>(mkp(
            hdecb, nullptr, WB + WO_DECHH, 0ull, 500, 1536, 512, 0,
            ghh, 1536, 0, dec_b_hh, nullptr, 0,
            nullptr, 0, nullptr, nullptr, nullptr, nullptr, 0, nullptr, lengths, flagp));
        k_apply_dec<<<1000, 256, 0, stream>>>(gih, ghh, hdec, hdecb, hsb, lengths, d);
    }

    // adaptive softmax — pass A: LSE partials (no logit stores)
    k_gemm<1><<<dim3(17, 16, 1), 256, 0, stream>>>(mkp(
        hsb, nullptr, WB + WO_W1, 0ull, NROW_, NTOTC, 512, NH_,
        nullptr, 0, 0, nullptr, nullptr, 0, nullptr, 0,
        stats, p0b, p1b, lsep, 0, nullptr, lengths, flagp));
    k_gemm<2><<<dim3(63, 16, 1), 256, 0, stream>>>(mkp(
        p0b, nullptr, WB + WO_T0O, 0ull, NROW_, 8000, 128, 8000,
        nullptr, 0, 0, nullptr, nullptr, 0, nullptr, 0,
        stats, nullptr, nullptr, lsep, 17, nullptr, lengths, flagp));
    k_gemm<2><<<dim3(172, 16, 1), 256, 0, stream>>>(mkp(
        p1b, nullptr, WB + WO_T1O, 0ull, NROW_, 22000, 32, 22000,
        nullptr, 0, 0, nullptr, nullptr, 0, nullptr, 0,
        stats, nullptr, nullptr, lsep, 80, nullptr, lengths, flagp));

    k_corr2<<<8, 256, 0, stream>>>(lsep, stats, corr);

    // pass B: recompute + store corrected log-probs directly to out
    k_gemm<3><<<dim3(16, 16, 1), 256, 0, stream>>>(mkp(
        hsb, nullptr, WB + WO_W1, 0ull, NROW_, C0_, 512, 0,
        nullptr, 0, 0, nullptr, nullptr, 0, out, 0,
        nullptr, nullptr, nullptr, nullptr, 0, corr, lengths, flagp));
    k_gemm<4><<<dim3(63, 16, 1), 256, 0, stream>>>(mkp(
        p0b, nullptr, WB + WO_T0O, 0ull, NROW_, 8000, 128, 0,
        nullptr, 0, 0, nullptr, nullptr, 0, out, C0_,
        nullptr, nullptr, nullptr, nullptr, 0, corr, lengths, flagp));
    k_gemm<5><<<dim3(172, 16, 1), 256, 0, stream>>>(mkp(
        p1b, nullptr, WB + WO_T1O, 0ull, NROW_, 22000, 32, 0,
        nullptr, 0, 0, nullptr, nullptr, 0, out, C1_,
        nullptr, nullptr, nullptr, nullptr, 0, corr, lengths, flagp));
}